// Round 17
// baseline (219.598 us; speedup 1.0000x reference)
//
#include <hip/hip_runtime.h>
#include <hip/hip_bf16.h>
#include <math.h>

typedef __bf16 bf16;
typedef __bf16 bf16x4 __attribute__((ext_vector_type(4)));
typedef __bf16 bf16x8 __attribute__((ext_vector_type(8)));
typedef float f32x4 __attribute__((ext_vector_type(4)));

#define MFMA16(a, b, c) __builtin_amdgcn_mfma_f32_16x16x32_bf16(a, b, c, 0, 0, 0)

__device__ __forceinline__ void gload16(const void* g, void* l) {
    __builtin_amdgcn_global_load_lds(
        (const __attribute__((address_space(1))) void*)g,
        (__attribute__((address_space(3))) void*)l, 16, 0, 0);
}

// ---------------------------------------------------------------- casts
// one launch for x + all four weights (each chunk = 8 f32 -> 8 bf16)
__global__ void cast_all(const float* __restrict__ x, const float* __restrict__ Wq,
                         const float* __restrict__ Wk, const float* __restrict__ Wv,
                         const float* __restrict__ Wp, bf16* __restrict__ x_bf,
                         bf16* __restrict__ wqkv, bf16* __restrict__ wp) {
    int i = blockIdx.x * blockDim.x + threadIdx.x;   // 0..1572863
    const float* src; bf16* dst; size_t loc;
    if (i < 1048576) {                               // x: 8M elems
        src = x; dst = x_bf; loc = i;
    } else {
        int c = i - 1048576;                         // weights: 4 x 1M elems
        int mat = c >> 17, l = c & 131071;
        src = (mat == 0) ? Wq : (mat == 1) ? Wk : (mat == 2) ? Wv : Wp;
        dst = (mat == 3) ? wp : (wqkv + (size_t)mat * 1048576);
        loc = l;
    }
    const float4* s = (const float4*)src + loc * 2;
    float4 v0 = s[0], v1 = s[1];
    bf16x8 o;
    o[0] = (bf16)v0.x; o[1] = (bf16)v0.y; o[2] = (bf16)v0.z; o[3] = (bf16)v0.w;
    o[4] = (bf16)v1.x; o[5] = (bf16)v1.y; o[6] = (bf16)v1.z; o[7] = (bf16)v1.w;
    *(bf16x8*)(dst + loc * 8) = o;
}

// ---------------------------------------------------------------- GEMM core
__device__ __forceinline__ void gemm_mainloop(
    const bf16* __restrict__ A, const bf16* __restrict__ W,
    int tm, int tn, int K, bf16* As, bf16* Bs,
    f32x4 acc[4][4], int lane, int wave, int wr, int wc) {
    for (int k0 = 0; k0 < K; k0 += 64) {
#pragma unroll
        for (int it = 0; it < 4; ++it) {
            int o = it * 4096 + wave * 1024 + lane * 16;
            int L = o ^ (((o >> 7) & 7) << 4);
            int row = L >> 7, colb = L & 127;
            gload16((const char*)A + ((size_t)(tm + row) * K + k0) * 2 + colb,
                    (char*)As + it * 4096 + wave * 1024);
            gload16((const char*)W + ((size_t)(tn + row) * K + k0) * 2 + colb,
                    (char*)Bs + it * 4096 + wave * 1024);
        }
        __syncthreads();
#pragma unroll
        for (int kk = 0; kk < 64; kk += 32) {
            bf16x8 a[4], b[4];
#pragma unroll
            for (int i = 0; i < 4; ++i) {
                int row = wr * 64 + i * 16 + (lane & 15);
                int byte = (row * 128 + kk * 2 + ((lane >> 4) * 16)) ^ ((row & 7) << 4);
                a[i] = *(const bf16x8*)((const char*)As + byte);
            }
#pragma unroll
            for (int j = 0; j < 4; ++j) {
                int row = wc * 64 + j * 16 + (lane & 15);
                int byte = (row * 128 + kk * 2 + ((lane >> 4) * 16)) ^ ((row & 7) << 4);
                b[j] = *(const bf16x8*)((const char*)Bs + byte);
            }
#pragma unroll
            for (int i = 0; i < 4; ++i)
#pragma unroll
                for (int j = 0; j < 4; ++j)
                    acc[i][j] = MFMA16(a[i], b[j], acc[i][j]);
        }
        __syncthreads();
    }
}

// QKV projection into qkv[3][64]...; Q pre-scaled by 0.25 (= H^-0.5).
// Q,K stored [bh][t][s]; V stored TRANSPOSED [bh][s][t], transposed on-chip
// through the (dead) As/Bs LDS so global stores are 256B-contiguous runs.
// Grid: flat 1536, XCD-clustered (each XCD gets 8 contiguous tm-rows).
__global__ void gemm_qkv(const bf16* __restrict__ A, const bf16* __restrict__ W,
                         bf16* __restrict__ qkv) {
    __shared__ bf16 SM[128 * 128];   // As | Bs during mainloop; T afterwards
    bf16* As = SM;
    bf16* Bs = SM + 8192;
    const int tid = threadIdx.x;
    const int lane = tid & 63, wave = tid >> 6;
    const int wr = wave >> 1, wc = wave & 1;
    const int l15 = lane & 15, hi = lane >> 4;
    const int d = blockIdx.x;
    const int flat = (d & 7) * 192 + (d >> 3);   // XCD-cluster: same-tm band per XCD
    const int tn = (flat % 24) * 128, tm = (flat / 24) * 128;
    f32x4 acc[4][4] = {};
    gemm_mainloop(A, W, tm, tn, 1024, As, Bs, acc, lane, wave, wr, wc);
    const int mat = tn >> 10;             // block-uniform
    if (mat == 2) {
        // transpose tile through LDS: T[c][t], byte = (c*256 + t*2) ^ ((c&7)<<4)
#pragma unroll
        for (int i = 0; i < 4; ++i)
#pragma unroll
            for (int r = 0; r < 4; ++r) {
                int tl = wr * 64 + i * 16 + hi * 4 + r;
#pragma unroll
                for (int j = 0; j < 4; ++j) {
                    int c = wc * 64 + j * 16 + l15;
                    int byte = (c * 256 + tl * 2) ^ ((c & 7) << 4);
                    *(bf16*)((char*)SM + byte) = (bf16)acc[i][j][r];
                }
            }
        __syncthreads();
        // store V^T rows: 16 lanes x 16B = 256B contiguous per row
        const int b16 = (tm >> 11) * 16, tmod = tm & 2047;
#pragma unroll
        for (int pass = 0; pass < 8; ++pass) {
            int c = (tid >> 4) + pass * 16;
            int h = ((tn + c) >> 6) & 15, s = c & 63;
            int byte = (c * 256 + (tid & 15) * 16) ^ ((c & 7) << 4);
            bf16x8 v = *(const bf16x8*)((const char*)SM + byte);
            size_t base = (size_t)(128 + b16 + h) * 131072 + (size_t)s * 2048 + tmod;
            *(bf16x8*)(qkv + base + (tid & 15) * 8) = v;
        }
    } else {
        const float scale = (mat == 0) ? 0.25f : 1.0f;
#pragma unroll
        for (int i = 0; i < 4; ++i)
#pragma unroll
            for (int r = 0; r < 4; ++r) {
                int m = tm + wr * 64 + i * 16 + hi * 4 + r;
                int b_ = m >> 11, t = m & 2047;
#pragma unroll
                for (int j = 0; j < 4; ++j) {
                    int n = tn + wc * 64 + j * 16 + l15;
                    int h = (n >> 6) & 15, s = n & 63;
                    qkv[(size_t)(mat * 64 + b_ * 16 + h) * 131072 + (size_t)t * 64 + s] =
                        (bf16)(acc[i][j][r] * scale);
                }
            }
    }
}

// Output projection + bias, fp32 out. Flat grid 512, XCD-clustered.
__global__ void gemm_out(const bf16* __restrict__ A, const bf16* __restrict__ W,
                         const float* __restrict__ bias, float* __restrict__ out) {
    __shared__ bf16 As[128 * 64];
    __shared__ bf16 Bs[128 * 64];
    const int lane = threadIdx.x & 63, wave = threadIdx.x >> 6;
    const int wr = wave >> 1, wc = wave & 1;
    const int d = blockIdx.x;
    const int flat = (d & 7) * 64 + (d >> 3);
    const int tn = (flat & 7) * 128, tm = (flat >> 3) * 128;
    f32x4 acc[4][4] = {};
    gemm_mainloop(A, W, tm, tn, 1024, As, Bs, acc, lane, wave, wr, wc);
#pragma unroll
    for (int i = 0; i < 4; ++i)
#pragma unroll
        for (int r = 0; r < 4; ++r) {
            int m = tm + wr * 64 + i * 16 + (lane >> 4) * 4 + r;
#pragma unroll
            for (int j = 0; j < 4; ++j) {
                int n = tn + wc * 64 + j * 16 + (lane & 15);
                out[(size_t)m * 1024 + n] = acc[i][j][r] + bias[n];
            }
        }
}

// ---------------------------------------------------------------- attention
// Swapped-operand attn; K fragments read DIRECTLY FROM GLOBAL (L2-resident,
// XCD-clustered) — no K staging, no Ks LDS. V^T staged via global_load_lds
// into XOR-swizzled [64][64]. P packed b64 writes. LDS 16 KB.
__global__ __launch_bounds__(256, 4)
void attn_kernel(const bf16* __restrict__ qkv, bf16* __restrict__ attn_out) {
    const int wgid = blockIdx.x;
    const int qp = (wgid >> 3) & 15;                    // 0..15
    const int bh = ((wgid & 7) << 3) | (wgid >> 7);     // 0..63, clustered per XCD
    const int tid = threadIdx.x;
    const int lane = tid & 63, wave = tid >> 6;
    const int l15 = lane & 15, hi = lane >> 4;
    const bf16* Qp = qkv + (size_t)bh * 131072;
    const bf16* Kp = qkv + (size_t)(64 + bh) * 131072;
    const bf16* Vt = qkv + (size_t)(128 + bh) * 131072;   // [s][t] transposed

    __shared__ bf16 VsBuf[4096];
    __shared__ bf16 PsBuf[4096];

    // V^T stage source offsets (swizzled source, linear LDS dest)
    int vt_off[2];
#pragma unroll
    for (int c = 0; c < 2; ++c) {
        int i = c * 256 + tid;
        int o = i * 16;
        int row = i >> 3;
        int colb = (o ^ ((row & 7) << 4)) & 127;
        vt_off[c] = row * 4096 + colb;    // V^T: row=s, stride 4096 B (t-major)
    }

    const int b_ = bh >> 4, h = bh & 15;

    for (int pass = 0; pass < 2; ++pass) {
        const int qi = pass ? (31 - qp) : qp;
        bf16x8 qf[2];
        {
            int row = qi * 64 + wave * 16 + l15;
#pragma unroll
            for (int ks = 0; ks < 2; ++ks)
                qf[ks] = *(const bf16x8*)(Qp + (size_t)row * 64 + ks * 32 + hi * 8);
        }
        f32x4 o_acc[4] = {};
        float l_run = 0.f;                  // per-lane scalar (q-row = lane&15)

        const int nkt = qi + 1;
        for (int kt = 0; kt < nkt; ++kt) {
            __syncthreads();   // prior tile (or pass) fully consumed
#pragma unroll
            for (int c = 0; c < 2; ++c)
                gload16((const char*)Vt + (size_t)kt * 128 + vt_off[c],
                        (char*)VsBuf + c * 4096 + wave * 1024);
            __syncthreads();   // V staged by all waves (vmcnt drained at barrier)

            // S^T = K Q^T: K fragments straight from global (L2-hit).
            // kb elements == the former LDS read: K[key][ks*32 + hi*8 ..]
            f32x4 sc[4] = {};
#pragma unroll
            for (int ks = 0; ks < 2; ++ks)
#pragma unroll
                for (int kf = 0; kf < 4; ++kf) {
                    bf16x8 kb = *(const bf16x8*)(Kp +
                        (size_t)(kt * 64 + kf * 16 + l15) * 64 + ks * 32 + hi * 8);
                    sc[kf] = MFMA16(kb, qf[ks], sc[kf]);   // SWAPPED operands
                }

            // lane-local max-free softmax: q-row = lane&15, key from regs
            if (kt == qi) {
                int row_g = qi * 64 + wave * 16 + l15;
#pragma unroll
                for (int kf = 0; kf < 4; ++kf)
#pragma unroll
                    for (int r = 0; r < 4; ++r) {
                        int key_g = kt * 64 + kf * 16 + hi * 4 + r;
                        float p = (key_g > row_g) ? 0.f : __expf(sc[kf][r]);
                        sc[kf][r] = p;
                        l_run += p;
                    }
            } else {
#pragma unroll
                for (int kf = 0; kf < 4; ++kf)
#pragma unroll
                    for (int r = 0; r < 4; ++r) {
                        float p = __expf(sc[kf][r]);
                        sc[kf][r] = p;
                        l_run += p;
                    }
            }

            // P -> LDS [qrow][key], packed 4-key ds_write_b64 per kf
#pragma unroll
            for (int kf = 0; kf < 4; ++kf) {
                bf16x4 pk;
#pragma unroll
                for (int r = 0; r < 4; ++r) pk[r] = (bf16)sc[kf][r];
                int row = wave * 16 + l15;
                int byte = (row * 128 + kf * 32 + hi * 8) ^ (((row >> 1) & 7) << 4);
                *(bf16x4*)((char*)PsBuf + byte) = pk;
            }
            asm volatile("s_waitcnt lgkmcnt(0)" ::: "memory");
            __builtin_amdgcn_sched_barrier(0);

            // O^T += V^T P^T  (swapped: A=V^T frag, B=P frag)
#pragma unroll
            for (int ks = 0; ks < 2; ++ks) {
                int prow = wave * 16 + l15;
                int pbyte = (prow * 128 + ks * 64 + hi * 16) ^ (((prow >> 1) & 7) << 4);
                bf16x8 pa = *(const bf16x8*)((const char*)PsBuf + pbyte);
#pragma unroll
                for (int sf = 0; sf < 4; ++sf) {
                    int srow = sf * 16 + l15;
                    int vbyte = (srow * 128 + ks * 64 + hi * 16) ^ ((srow & 7) << 4);
                    bf16x8 vb = *(const bf16x8*)((const char*)VsBuf + vbyte);
                    o_acc[sf] = MFMA16(vb, pa, o_acc[sf]);   // SWAPPED operands
                }
            }
        }

        // epilogue: l is per-lane partial for q-row=lane&15; sum across the
        // 4 lane-groups (xor 16, 32). O^T regs: q-row=lane&15, s=sf*16+hi*4+r.
        float l = l_run;
        l += __shfl_xor(l, 16, 64);
        l += __shfl_xor(l, 32, 64);
        float inv = 1.0f / l;
        int t = qi * 64 + wave * 16 + l15;
        size_t base = ((size_t)(b_ * 2048 + t)) * 1024 + h * 64;
#pragma unroll
        for (int sf = 0; sf < 4; ++sf) {
            bf16x4 ov;
#pragma unroll
            for (int r = 0; r < 4; ++r) ov[r] = (bf16)(o_acc[sf][r] * inv);
            *(bf16x4*)(attn_out + base + sf * 16 + hi * 4) = ov;
        }
    }
}

// ---------------------------------------------------------------- launch
extern "C" void kernel_launch(void* const* d_in, const int* in_sizes, int n_in,
                              void* d_out, int out_size, void* d_ws, size_t ws_size,
                              hipStream_t stream) {
    const float* x  = (const float*)d_in[0];
    const float* Wq = (const float*)d_in[1];
    const float* Wk = (const float*)d_in[2];
    const float* Wv = (const float*)d_in[3];
    const float* Wp = (const float*)d_in[4];
    const float* bp = (const float*)d_in[5];
    float* out = (float*)d_out;

    char* ws = (char*)d_ws;
    bf16* x_bf   = (bf16*)(ws);                    // 16,777,216 B
    bf16* wqkv   = (bf16*)(ws + 16777216);         //  6,291,456 B
    bf16* wp_bf  = (bf16*)(ws + 23068672);         //  2,097,152 B
    bf16* qkv    = (bf16*)(ws + 25165824);         // 50,331,648 B
    bf16* attn_b = (bf16*)(ws + 75497472);         // 16,777,216 B

    cast_all<<<dim3(6144), 256, 0, stream>>>(x, Wq, Wk, Wv, Wp, x_bf, wqkv, wp_bf);

    gemm_qkv<<<dim3(1536), 256, 0, stream>>>(x_bf, wqkv, qkv);
    attn_kernel<<<dim3(1024), 256, 0, stream>>>(qkv, attn_b);
    gemm_out<<<dim3(512), 256, 0, stream>>>(attn_b, wp_bf, bp, out);
}

// Round 18
// 146.656 us; speedup vs baseline: 1.4974x; 1.4974x over previous
//
#include <hip/hip_runtime.h>
#include <hip/hip_bf16.h>
#include <math.h>

typedef __bf16 bf16;
typedef __bf16 bf16x4 __attribute__((ext_vector_type(4)));
typedef __bf16 bf16x8 __attribute__((ext_vector_type(8)));
typedef float f32x4 __attribute__((ext_vector_type(4)));

#define MFMA16(a, b, c) __builtin_amdgcn_mfma_f32_16x16x32_bf16(a, b, c, 0, 0, 0)

__device__ __forceinline__ void gload16(const void* g, void* l) {
    __builtin_amdgcn_global_load_lds(
        (const __attribute__((address_space(1))) void*)g,
        (__attribute__((address_space(3))) void*)l, 16, 0, 0);
}

// ---------------------------------------------------------------- casts
// one launch for x + all four weights (each chunk = 8 f32 -> 8 bf16)
__global__ void cast_all(const float* __restrict__ x, const float* __restrict__ Wq,
                         const float* __restrict__ Wk, const float* __restrict__ Wv,
                         const float* __restrict__ Wp, bf16* __restrict__ x_bf,
                         bf16* __restrict__ wqkv, bf16* __restrict__ wp) {
    int i = blockIdx.x * blockDim.x + threadIdx.x;   // 0..1572863
    const float* src; bf16* dst; size_t loc;
    if (i < 1048576) {                               // x: 8M elems
        src = x; dst = x_bf; loc = i;
    } else {
        int c = i - 1048576;                         // weights: 4 x 1M elems
        int mat = c >> 17, l = c & 131071;
        src = (mat == 0) ? Wq : (mat == 1) ? Wk : (mat == 2) ? Wv : Wp;
        dst = (mat == 3) ? wp : (wqkv + (size_t)mat * 1048576);
        loc = l;
    }
    const float4* s = (const float4*)src + loc * 2;
    float4 v0 = s[0], v1 = s[1];
    bf16x8 o;
    o[0] = (bf16)v0.x; o[1] = (bf16)v0.y; o[2] = (bf16)v0.z; o[3] = (bf16)v0.w;
    o[4] = (bf16)v1.x; o[5] = (bf16)v1.y; o[6] = (bf16)v1.z; o[7] = (bf16)v1.w;
    *(bf16x8*)(dst + loc * 8) = o;
}

// ---------------------------------------------------------------- GEMM core
__device__ __forceinline__ void gemm_mainloop(
    const bf16* __restrict__ A, const bf16* __restrict__ W,
    int tm, int tn, int K, bf16* As, bf16* Bs,
    f32x4 acc[4][4], int lane, int wave, int wr, int wc) {
    for (int k0 = 0; k0 < K; k0 += 64) {
#pragma unroll
        for (int it = 0; it < 4; ++it) {
            int o = it * 4096 + wave * 1024 + lane * 16;
            int L = o ^ (((o >> 7) & 7) << 4);
            int row = L >> 7, colb = L & 127;
            gload16((const char*)A + ((size_t)(tm + row) * K + k0) * 2 + colb,
                    (char*)As + it * 4096 + wave * 1024);
            gload16((const char*)W + ((size_t)(tn + row) * K + k0) * 2 + colb,
                    (char*)Bs + it * 4096 + wave * 1024);
        }
        __syncthreads();
#pragma unroll
        for (int kk = 0; kk < 64; kk += 32) {
            bf16x8 a[4], b[4];
#pragma unroll
            for (int i = 0; i < 4; ++i) {
                int row = wr * 64 + i * 16 + (lane & 15);
                int byte = (row * 128 + kk * 2 + ((lane >> 4) * 16)) ^ ((row & 7) << 4);
                a[i] = *(const bf16x8*)((const char*)As + byte);
            }
#pragma unroll
            for (int j = 0; j < 4; ++j) {
                int row = wc * 64 + j * 16 + (lane & 15);
                int byte = (row * 128 + kk * 2 + ((lane >> 4) * 16)) ^ ((row & 7) << 4);
                b[j] = *(const bf16x8*)((const char*)Bs + byte);
            }
#pragma unroll
            for (int i = 0; i < 4; ++i)
#pragma unroll
                for (int j = 0; j < 4; ++j)
                    acc[i][j] = MFMA16(a[i], b[j], acc[i][j]);
        }
        __syncthreads();
    }
}

// QKV projection into qkv[3][64]...; Q pre-scaled by 0.25 (= H^-0.5).
// Q,K stored [bh][t][s]; V stored TRANSPOSED [bh][s][t], transposed on-chip
// through the (dead) As/Bs LDS so global stores are 256B-contiguous runs.
// Grid: flat 1536, XCD-clustered (each XCD gets 8 contiguous tm-rows).
__global__ void gemm_qkv(const bf16* __restrict__ A, const bf16* __restrict__ W,
                         bf16* __restrict__ qkv) {
    __shared__ bf16 SM[128 * 128];   // As | Bs during mainloop; T afterwards
    bf16* As = SM;
    bf16* Bs = SM + 8192;
    const int tid = threadIdx.x;
    const int lane = tid & 63, wave = tid >> 6;
    const int wr = wave >> 1, wc = wave & 1;
    const int l15 = lane & 15, hi = lane >> 4;
    const int d = blockIdx.x;
    const int flat = (d & 7) * 192 + (d >> 3);   // XCD-cluster: same-tm band per XCD
    const int tn = (flat % 24) * 128, tm = (flat / 24) * 128;
    f32x4 acc[4][4] = {};
    gemm_mainloop(A, W, tm, tn, 1024, As, Bs, acc, lane, wave, wr, wc);
    const int mat = tn >> 10;             // block-uniform
    if (mat == 2) {
        // transpose tile through LDS: T[c][t], byte = (c*256 + t*2) ^ ((c&7)<<4)
#pragma unroll
        for (int i = 0; i < 4; ++i)
#pragma unroll
            for (int r = 0; r < 4; ++r) {
                int tl = wr * 64 + i * 16 + hi * 4 + r;
#pragma unroll
                for (int j = 0; j < 4; ++j) {
                    int c = wc * 64 + j * 16 + l15;
                    int byte = (c * 256 + tl * 2) ^ ((c & 7) << 4);
                    *(bf16*)((char*)SM + byte) = (bf16)acc[i][j][r];
                }
            }
        __syncthreads();
        // store V^T rows: 16 lanes x 16B = 256B contiguous per row
        const int b16 = (tm >> 11) * 16, tmod = tm & 2047;
#pragma unroll
        for (int pass = 0; pass < 8; ++pass) {
            int c = (tid >> 4) + pass * 16;
            int h = ((tn + c) >> 6) & 15, s = c & 63;
            int byte = (c * 256 + (tid & 15) * 16) ^ ((c & 7) << 4);
            bf16x8 v = *(const bf16x8*)((const char*)SM + byte);
            size_t base = (size_t)(128 + b16 + h) * 131072 + (size_t)s * 2048 + tmod;
            *(bf16x8*)(qkv + base + (tid & 15) * 8) = v;
        }
    } else {
        const float scale = (mat == 0) ? 0.25f : 1.0f;
#pragma unroll
        for (int i = 0; i < 4; ++i)
#pragma unroll
            for (int r = 0; r < 4; ++r) {
                int m = tm + wr * 64 + i * 16 + hi * 4 + r;
                int b_ = m >> 11, t = m & 2047;
#pragma unroll
                for (int j = 0; j < 4; ++j) {
                    int n = tn + wc * 64 + j * 16 + l15;
                    int h = (n >> 6) & 15, s = n & 63;
                    qkv[(size_t)(mat * 64 + b_ * 16 + h) * 131072 + (size_t)t * 64 + s] =
                        (bf16)(acc[i][j][r] * scale);
                }
            }
    }
}

// Output projection + bias, fp32 out. Flat grid 512, XCD-clustered.
__global__ void gemm_out(const bf16* __restrict__ A, const bf16* __restrict__ W,
                         const float* __restrict__ bias, float* __restrict__ out) {
    __shared__ bf16 As[128 * 64];
    __shared__ bf16 Bs[128 * 64];
    const int lane = threadIdx.x & 63, wave = threadIdx.x >> 6;
    const int wr = wave >> 1, wc = wave & 1;
    const int d = blockIdx.x;
    const int flat = (d & 7) * 64 + (d >> 3);
    const int tn = (flat & 7) * 128, tm = (flat >> 3) * 128;
    f32x4 acc[4][4] = {};
    gemm_mainloop(A, W, tm, tn, 1024, As, Bs, acc, lane, wave, wr, wc);
#pragma unroll
    for (int i = 0; i < 4; ++i)
#pragma unroll
        for (int r = 0; r < 4; ++r) {
            int m = tm + wr * 64 + i * 16 + (lane >> 4) * 4 + r;
#pragma unroll
            for (int j = 0; j < 4; ++j) {
                int n = tn + wc * 64 + j * 16 + (lane & 15);
                out[(size_t)m * 1024 + n] = acc[i][j][r] + bias[n];
            }
        }
}

// ---------------------------------------------------------------- attention
// (round-16 kernel + T5 setprio around MFMA clusters)
// Swapped-operand: S^T = mfma(K,Q) puts q-row on lane&15, keys in regs ->
// lane-local softmax, P packs 4 bf16/ds_write_b64; PV swapped keeps q-row on
// lanes. K,V^T staged via global_load_lds into XOR-swizzled [64][64].
__global__ __launch_bounds__(256, 4)
void attn_kernel(const bf16* __restrict__ qkv, bf16* __restrict__ attn_out) {
    const int wgid = blockIdx.x;
    const int qp = (wgid >> 3) & 15;                    // 0..15
    const int bh = ((wgid & 7) << 3) | (wgid >> 7);     // 0..63, clustered per XCD
    const int tid = threadIdx.x;
    const int lane = tid & 63, wave = tid >> 6;
    const int l15 = lane & 15, hi = lane >> 4;
    const bf16* Qp = qkv + (size_t)bh * 131072;
    const bf16* Kp = qkv + (size_t)(64 + bh) * 131072;
    const bf16* Vt = qkv + (size_t)(128 + bh) * 131072;   // [s][t] transposed

    __shared__ bf16 KsBuf[4096];
    __shared__ bf16 VsBuf[4096];
    __shared__ bf16 PsBuf[4096];

    // stage source offsets (swizzled source, linear LDS dest)
    int k_off[2], vt_off[2];
#pragma unroll
    for (int c = 0; c < 2; ++c) {
        int i = c * 256 + tid;
        int o = i * 16;
        int row = i >> 3;
        int colb = (o ^ ((row & 7) << 4)) & 127;
        k_off[c]  = row * 128  + colb;    // K: row=key, stride 128 B within tile
        vt_off[c] = row * 4096 + colb;    // V^T: row=s, stride 4096 B (t-major)
    }

    const int b_ = bh >> 4, h = bh & 15;

    for (int pass = 0; pass < 2; ++pass) {
        const int qi = pass ? (31 - qp) : qp;
        bf16x8 qf[2];
        {
            int row = qi * 64 + wave * 16 + l15;
#pragma unroll
            for (int ks = 0; ks < 2; ++ks)
                qf[ks] = *(const bf16x8*)(Qp + (size_t)row * 64 + ks * 32 + hi * 8);
        }
        f32x4 o_acc[4] = {};
        float l_run = 0.f;                  // per-lane scalar (q-row = lane&15)

        const int nkt = qi + 1;
        for (int kt = 0; kt < nkt; ++kt) {
            __syncthreads();   // prior tile (or pass) fully consumed
#pragma unroll
            for (int c = 0; c < 2; ++c) {
                gload16((const char*)Kp + (size_t)kt * 8192 + k_off[c],
                        (char*)KsBuf + c * 4096 + wave * 1024);
                gload16((const char*)Vt + (size_t)kt * 128 + vt_off[c],
                        (char*)VsBuf + c * 4096 + wave * 1024);
            }
            __syncthreads();   // staged by all waves (vmcnt drained at barrier)

            // S^T = K Q^T: col=lane&15=q-row, row(regs)=key (per 16-key frag kf)
            f32x4 sc[4] = {};
            __builtin_amdgcn_s_setprio(1);
#pragma unroll
            for (int ks = 0; ks < 2; ++ks)
#pragma unroll
                for (int kf = 0; kf < 4; ++kf) {
                    int row = kf * 16 + l15;
                    int byte = (row * 128 + ks * 64 + hi * 16) ^ ((row & 7) << 4);
                    bf16x8 kb = *(const bf16x8*)((const char*)KsBuf + byte);
                    sc[kf] = MFMA16(kb, qf[ks], sc[kf]);   // SWAPPED operands
                }
            __builtin_amdgcn_s_setprio(0);

            // lane-local max-free softmax: q-row = lane&15, key from regs
            if (kt == qi) {
                int row_g = qi * 64 + wave * 16 + l15;
#pragma unroll
                for (int kf = 0; kf < 4; ++kf)
#pragma unroll
                    for (int r = 0; r < 4; ++r) {
                        int key_g = kt * 64 + kf * 16 + hi * 4 + r;
                        float p = (key_g > row_g) ? 0.f : __expf(sc[kf][r]);
                        sc[kf][r] = p;
                        l_run += p;
                    }
            } else {
#pragma unroll
                for (int kf = 0; kf < 4; ++kf)
#pragma unroll
                    for (int r = 0; r < 4; ++r) {
                        float p = __expf(sc[kf][r]);
                        sc[kf][r] = p;
                        l_run += p;
                    }
            }

            // P -> LDS [qrow][key], packed 4-key ds_write_b64 per kf
#pragma unroll
            for (int kf = 0; kf < 4; ++kf) {
                bf16x4 pk;
#pragma unroll
                for (int r = 0; r < 4; ++r) pk[r] = (bf16)sc[kf][r];
                int row = wave * 16 + l15;
                int byte = (row * 128 + kf * 32 + hi * 8) ^ (((row >> 1) & 7) << 4);
                *(bf16x4*)((char*)PsBuf + byte) = pk;
            }
            asm volatile("s_waitcnt lgkmcnt(0)" ::: "memory");
            __builtin_amdgcn_sched_barrier(0);

            // O^T += V^T P^T  (swapped: A=V^T frag, B=P frag; reads unchanged)
            __builtin_amdgcn_s_setprio(1);
#pragma unroll
            for (int ks = 0; ks < 2; ++ks) {
                int prow = wave * 16 + l15;
                int pbyte = (prow * 128 + ks * 64 + hi * 16) ^ (((prow >> 1) & 7) << 4);
                bf16x8 pa = *(const bf16x8*)((const char*)PsBuf + pbyte);
#pragma unroll
                for (int sf = 0; sf < 4; ++sf) {
                    int srow = sf * 16 + l15;
                    int vbyte = (srow * 128 + ks * 64 + hi * 16) ^ ((srow & 7) << 4);
                    bf16x8 vb = *(const bf16x8*)((const char*)VsBuf + vbyte);
                    o_acc[sf] = MFMA16(vb, pa, o_acc[sf]);   // SWAPPED operands
                }
            }
            __builtin_amdgcn_s_setprio(0);
        }

        // epilogue: l is per-lane partial for q-row=lane&15; sum across the
        // 4 lane-groups (xor 16, 32). O^T regs: q-row=lane&15, s=sf*16+hi*4+r.
        float l = l_run;
        l += __shfl_xor(l, 16, 64);
        l += __shfl_xor(l, 32, 64);
        float inv = 1.0f / l;
        int t = qi * 64 + wave * 16 + l15;
        size_t base = ((size_t)(b_ * 2048 + t)) * 1024 + h * 64;
#pragma unroll
        for (int sf = 0; sf < 4; ++sf) {
            bf16x4 ov;
#pragma unroll
            for (int r = 0; r < 4; ++r) ov[r] = (bf16)(o_acc[sf][r] * inv);
            *(bf16x4*)(attn_out + base + sf * 16 + hi * 4) = ov;
        }
    }
}

// ---------------------------------------------------------------- launch
extern "C" void kernel_launch(void* const* d_in, const int* in_sizes, int n_in,
                              void* d_out, int out_size, void* d_ws, size_t ws_size,
                              hipStream_t stream) {
    const float* x  = (const float*)d_in[0];
    const float* Wq = (const float*)d_in[1];
    const float* Wk = (const float*)d_in[2];
    const float* Wv = (const float*)d_in[3];
    const float* Wp = (const float*)d_in[4];
    const float* bp = (const float*)d_in[5];
    float* out = (float*)d_out;

    char* ws = (char*)d_ws;
    bf16* x_bf   = (bf16*)(ws);                    // 16,777,216 B
    bf16* wqkv   = (bf16*)(ws + 16777216);         //  6,291,456 B
    bf16* wp_bf  = (bf16*)(ws + 23068672);         //  2,097,152 B
    bf16* qkv    = (bf16*)(ws + 25165824);         // 50,331,648 B
    bf16* attn_b = (bf16*)(ws + 75497472);         // 16,777,216 B

    cast_all<<<dim3(6144), 256, 0, stream>>>(x, Wq, Wk, Wv, Wp, x_bf, wqkv, wp_bf);

    gemm_qkv<<<dim3(1536), 256, 0, stream>>>(x_bf, wqkv, qkv);
    attn_kernel<<<dim3(1024), 256, 0, stream>>>(qkv, attn_b);
    gemm_out<<<dim3(512), 256, 0, stream>>>(attn_b, wp_bf, bp, out);
}